// Round 16
// baseline (147.601 us; speedup 1.0000x reference)
//
#include <hip/hip_runtime.h>
#include <math.h>

#define BATCH 4
#define CH    256
#define CQK   32
#define NPIX  4096   // 64*64
#define NT    32     // KV steps of 128 keys each
#define LOG2E 1.4426950408889634f

typedef __attribute__((ext_vector_type(8))) short short8;   // 8 bf16 (4 VGPRs)
typedef __attribute__((ext_vector_type(4))) float f32x4;

static __device__ __forceinline__ unsigned short f2bf(float f) {
    unsigned u = __builtin_bit_cast(unsigned, f);
    u = (u + 0x7fffu + ((u >> 16) & 1u)) >> 16;   // RNE
    return (unsigned short)u;
}
static __device__ __forceinline__ float bf2f(unsigned short s) {
    unsigned u = ((unsigned)s) << 16;
    return __builtin_bit_cast(float, u);
}
static __device__ __forceinline__ float exp2_fast(float x) {
    float r; asm("v_exp_f32 %0, %1" : "=v"(r) : "v"(x)); return r;
}
static __device__ __forceinline__ unsigned cvt_pk_bf16(float lo, float hi) {
    unsigned r; asm("v_cvt_pk_bf16_f32 %0, %1, %2" : "=v"(r) : "v"(lo), "v"(hi)); return r;
}
static __device__ __forceinline__ void barrier_lgkm_only() {
    asm volatile("s_waitcnt lgkmcnt(0)" ::: "memory");
    __builtin_amdgcn_s_barrier();
}

// ---------------------------------------------------------------------------
// Kernel 0: W -> bf16 hi/lo. Q rows pre-scaled by log2(e) (base-2 softmax).
// ---------------------------------------------------------------------------
__global__ __launch_bounds__(256) void wcvt_kernel(
    const float* __restrict__ wq, const float* __restrict__ wk,
    const float* __restrict__ wv,
    unsigned short* __restrict__ Wh, unsigned short* __restrict__ Wl)
{
    int idx = blockIdx.x * 256 + threadIdx.x;   // 0..81919
    int r = idx >> 8, c = idx & 255;
    float f;
    if (r < 32)       f = wq[r * 256 + c] * LOG2E;
    else if (r < 64)  f = wk[(r - 32) * 256 + c];
    else              f = wv[(r - 64) * 256 + c];
    unsigned short h = f2bf(f);
    Wh[idx] = h;
    Wl[idx] = f2bf(f - bf2f(h));
}

// ---------------------------------------------------------------------------
// Kernel 1: q/k/v projections, compensated-bf16 MFMA GEMM, n-tile = 64.
// ---------------------------------------------------------------------------
__global__ __launch_bounds__(256) void qkv_kernel(
    const float* __restrict__ x,
    const float* __restrict__ bq, const float* __restrict__ bk,
    const float* __restrict__ bv,
    const unsigned short* __restrict__ Wh, const unsigned short* __restrict__ Wl,
    unsigned short* __restrict__ Qh, unsigned short* __restrict__ Kh,
    unsigned short* __restrict__ Vb)
{
    extern __shared__ char xsmem[];
    char* const Xh = xsmem;              // 64 rows x 512B
    char* const Xl = xsmem + 32768;

    const int b  = blockIdx.y;
    const int n0 = blockIdx.x * 64;
    const int t  = threadIdx.x;

    #pragma unroll
    for (int rep = 0; rep < 8; ++rep) {
        int idx = rep * 256 + t;
        int cp = idx >> 4, n4 = idx & 15;        // cp = c/2
        int c = cp * 2;
        float4 a4 = *(const float4*)&x[((size_t)b * CH + c) * NPIX + n0 + n4 * 4];
        float4 b4 = *(const float4*)&x[((size_t)b * CH + c + 1) * NPIX + n0 + n4 * 4];
        #pragma unroll
        for (int u = 0; u < 4; ++u) {
            int n = n4 * 4 + u;
            float fa = (&a4.x)[u], fb = (&b4.x)[u];
            unsigned short ha = f2bf(fa), hb = f2bf(fb);
            unsigned short la = f2bf(fa - bf2f(ha)), lb = f2bf(fb - bf2f(hb));
            int off = n * 512 + (((c >> 3) * 16) ^ ((n & 7) << 4)) + (c & 7) * 2;
            *(unsigned*)(Xh + off) = (unsigned)ha | ((unsigned)hb << 16);
            *(unsigned*)(Xl + off) = (unsigned)la | ((unsigned)lb << 16);
        }
    }
    __syncthreads();

    const int w = t >> 6, l = t & 63, g = l >> 4, m = l & 15;

    for (int dt = 0; dt < 5; ++dt) {
        const int d0 = w * 80 + dt * 16;

        short8 wh[8], wl[8];
        #pragma unroll
        for (int ks = 0; ks < 8; ++ks) {
            size_t off = (size_t)(d0 + m) * 256 + ks * 32 + g * 8;
            wh[ks] = __builtin_bit_cast(short8, *(const uint4*)&Wh[off]);
            wl[ks] = __builtin_bit_cast(short8, *(const uint4*)&Wl[off]);
        }

        f32x4 acc[4];
        #pragma unroll
        for (int nt = 0; nt < 4; ++nt) acc[nt] = (f32x4){0.f, 0.f, 0.f, 0.f};
        #pragma unroll
        for (int nt = 0; nt < 4; ++nt) {
            const int n = nt * 16 + m;
            #pragma unroll
            for (int ks = 0; ks < 8; ++ks) {
                int off = n * 512 + (((ks * 4 + g) * 16) ^ ((n & 7) << 4));
                short8 xh = __builtin_bit_cast(short8, *(const uint4*)(Xh + off));
                short8 xl = __builtin_bit_cast(short8, *(const uint4*)(Xl + off));
                acc[nt] = __builtin_amdgcn_mfma_f32_16x16x32_bf16(wh[ks], xh, acc[nt], 0, 0, 0);
                acc[nt] = __builtin_amdgcn_mfma_f32_16x16x32_bf16(wh[ks], xl, acc[nt], 0, 0, 0);
                acc[nt] = __builtin_amdgcn_mfma_f32_16x16x32_bf16(wl[ks], xh, acc[nt], 0, 0, 0);
            }
        }

        int kind;                      // 0=Q, 1=K, 2=V
        float4 bias;
        if (d0 < 32)      { kind = 0; bias = *(const float4*)&bq[d0 + g * 4];
                            bias.x *= LOG2E; bias.y *= LOG2E; bias.z *= LOG2E; bias.w *= LOG2E; }
        else if (d0 < 64) { kind = 1; bias = *(const float4*)&bk[d0 - 32 + g * 4]; }
        else              { kind = 2; bias = *(const float4*)&bv[d0 - 64 + g * 4]; }

        #pragma unroll
        for (int nt = 0; nt < 4; ++nt) {
            const int n = n0 + nt * 16 + m;
            if (kind == 2) {
                const int c0 = d0 - 64;
                #pragma unroll
                for (int r = 0; r < 4; ++r) {
                    float val = acc[nt][r] + (&bias.x)[r];
                    Vb[((size_t)b * CH + c0 + g * 4 + r) * NPIX + n] = f2bf(val);
                }
            } else {
                unsigned short hs[4];
                #pragma unroll
                for (int r = 0; r < 4; ++r)
                    hs[r] = f2bf(acc[nt][r] + (&bias.x)[r]);
                const int dcol = (d0 & 31) + g * 4;
                const size_t base = ((size_t)b * NPIX + n) * CQK + dcol;
                uint2 uh;
                uh.x = (unsigned)hs[0] | ((unsigned)hs[1] << 16);
                uh.y = (unsigned)hs[2] | ((unsigned)hs[3] << 16);
                if (kind == 0) *(uint2*)&Qh[base] = uh;
                else           *(uint2*)&Kh[base] = uh;
            }
        }
    }
}

// ---------------------------------------------------------------------------
// Kernel 2: flash attention, 2 KV steps per barrier, 4-phase buffers.
//   Producer runs steps 2T,2T+1 back-to-back (two independent chains per
//   barrier interval -> latency interleaving); consumer lags P by 2 steps
//   (every LDS handoff crosses >=1 barrier: K write@T for tiles 2T+2/2T+3
//   read@T+1; P write@s read@superstep+1; buffer pairs mod 4 disjoint).
//   Dynamic LDS 97.25KB: K 4x8KB | P 4x16KB | sFac 4x64 | sL.
// ---------------------------------------------------------------------------

#define PROD_STEP(S) do {                                                      \
    const int _idx = (S) & 3;                                                  \
    const char* kb = Kb + _idx * 8192;                                         \
    f32x4 sv[8];                                                               \
    _Pragma("unroll")                                                          \
    for (int jf = 0; jf < 8; ++jf) {                                           \
        short8 kh8 = __builtin_bit_cast(short8, *(const uint4*)&kb[            \
            jf * 1024 + m * 64 + ((g * 16) ^ (((m >> 1) & 3) << 4))]);         \
        f32x4 s = (f32x4){0.f, 0.f, 0.f, 0.f};                                 \
        s = __builtin_amdgcn_mfma_f32_16x16x32_bf16(kh8, qh, s, 0, 0, 0);      \
        sv[jf] = s;                                                            \
    }                                                                          \
    float s32[32];                                                             \
    _Pragma("unroll")                                                          \
    for (int jf = 0; jf < 8; ++jf)                                             \
        _Pragma("unroll")                                                      \
        for (int r = 0; r < 4; ++r) s32[jf * 4 + r] = sv[jf][r];               \
    float mx[16];                                                              \
    _Pragma("unroll")                                                          \
    for (int k = 0; k < 16; ++k) mx[k] = fmaxf(s32[k], s32[k + 16]);           \
    _Pragma("unroll")                                                          \
    for (int k = 0; k < 8; ++k) mx[k] = fmaxf(mx[k], mx[k + 8]);               \
    _Pragma("unroll")                                                          \
    for (int k = 0; k < 4; ++k) mx[k] = fmaxf(mx[k], mx[k + 4]);               \
    float tmax = fmaxf(fmaxf(mx[0], mx[2]), fmaxf(mx[1], mx[3]));              \
    float fac = 1.0f;                                                          \
    if (!__all(tmax <= m_run + 11.5f)) {                                       \
        float tc = fmaxf(tmax, __shfl_xor(tmax, 16));                          \
        tc = fmaxf(tc, __shfl_xor(tc, 32));                                    \
        float mt = fmaxf(m_run, tc);                                           \
        fac = exp2_fast(m_run - mt);                                           \
        m_run = mt;                                                            \
    }                                                                          \
    float p[32];                                                               \
    _Pragma("unroll")                                                          \
    for (int k = 0; k < 32; ++k) p[k] = exp2_fast(s32[k] - m_run);             \
    float sm[16];                                                              \
    _Pragma("unroll")                                                          \
    for (int k = 0; k < 16; ++k) sm[k] = p[k] + p[k + 16];                     \
    _Pragma("unroll")                                                          \
    for (int k = 0; k < 8; ++k) sm[k] = sm[k] + sm[k + 8];                     \
    _Pragma("unroll")                                                          \
    for (int k = 0; k < 4; ++k) sm[k] = sm[k] + sm[k + 4];                     \
    float tsum = (sm[0] + sm[2]) + (sm[1] + sm[3]);                            \
    tsum += __shfl_xor(tsum, 16);                                              \
    tsum += __shfl_xor(tsum, 32);                                              \
    l_run = l_run * fac + tsum;                                                \
    if (g == 0) sF[_idx * 64 + irow] = fac;                                    \
    char* pbw = Pb + _idx * 16384;                                             \
    _Pragma("unroll")                                                          \
    for (int jf = 0; jf < 8; ++jf) {                                           \
        uint2 u;                                                               \
        u.x = cvt_pk_bf16(p[jf * 4 + 0], p[jf * 4 + 1]);                       \
        u.y = cvt_pk_bf16(p[jf * 4 + 2], p[jf * 4 + 3]);                       \
        *(uint2*)(pbw + irow * 256 + ((jf * 32 + g * 8) ^ (m << 4))) = u;      \
    }                                                                          \
} while (0)

#define CONS_PV(S, VBUF, PF) do {                                              \
    const int _s  = (S);                                                       \
    const int _jb = _s * 128;                                                  \
    const char* pb = Pb + (_s & 3) * 16384;                                    \
    float ff[4];                                                               \
    _Pragma("unroll")                                                          \
    for (int f = 0; f < 4; ++f) ff[f] = sF[(_s & 3) * 64 + f * 16 + m];        \
    uint4 vB[8];                                                               \
    _Pragma("unroll")                                                          \
    for (int cf = 0; cf < 4; ++cf) {                                           \
        vB[cf * 2]     = *(const uint4*)&vrow[cf][_jb + 64 + g * 8];           \
        vB[cf * 2 + 1] = *(const uint4*)&vrow[cf][_jb + 96 + g * 8];           \
    }                                                                          \
    short8 pf[4][2];                                                           \
    _Pragma("unroll")                                                          \
    for (int f = 0; f < 4; ++f)                                                \
        _Pragma("unroll")                                                      \
        for (int k2 = 0; k2 < 2; ++k2)                                         \
            pf[f][k2] = __builtin_bit_cast(short8, *(const uint4*)(pb +        \
                (f * 16 + m) * 256 + ((k2 * 64 + g * 16) ^ (m << 4))));        \
    if (!__all(ff[0] == 1.f && ff[1] == 1.f && ff[2] == 1.f && ff[3] == 1.f)) { \
        _Pragma("unroll")                                                      \
        for (int cf = 0; cf < 4; ++cf)                                         \
            _Pragma("unroll")                                                  \
            for (int f = 0; f < 4; ++f) acc[cf][f] *= ff[f];                   \
    }                                                                          \
    _Pragma("unroll")                                                          \
    for (int cf = 0; cf < 4; ++cf) {                                           \
        short8 v0 = __builtin_bit_cast(short8, VBUF[cf * 2]);                  \
        short8 v1 = __builtin_bit_cast(short8, VBUF[cf * 2 + 1]);              \
        _Pragma("unroll")                                                      \
        for (int f = 0; f < 4; ++f) {                                          \
            f32x4 a = acc[cf][f];                                              \
            a = __builtin_amdgcn_mfma_f32_16x16x32_bf16(v0, pf[f][0], a, 0, 0, 0); \
            a = __builtin_amdgcn_mfma_f32_16x16x32_bf16(v1, pf[f][1], a, 0, 0, 0); \
            acc[cf][f] = a;                                                    \
        }                                                                      \
    }                                                                          \
    if (PF) {                                                                  \
        _Pragma("unroll")                                                      \
        for (int cf = 0; cf < 4; ++cf) {                                       \
            VBUF[cf * 2]     = *(const uint4*)&vrow[cf][_jb + 256 + g * 8];    \
            VBUF[cf * 2 + 1] = *(const uint4*)&vrow[cf][_jb + 288 + g * 8];    \
        }                                                                      \
    }                                                                          \
    short8 pg[4][2];                                                           \
    _Pragma("unroll")                                                          \
    for (int f = 0; f < 4; ++f)                                                \
        _Pragma("unroll")                                                      \
        for (int k2 = 0; k2 < 2; ++k2)                                         \
            pg[f][k2] = __builtin_bit_cast(short8, *(const uint4*)(pb +        \
                (f * 16 + m) * 256 + (((k2 + 2) * 64 + g * 16) ^ (m << 4))));  \
    _Pragma("unroll")                                                          \
    for (int cf = 0; cf < 4; ++cf) {                                           \
        short8 v0 = __builtin_bit_cast(short8, vB[cf * 2]);                    \
        short8 v1 = __builtin_bit_cast(short8, vB[cf * 2 + 1]);                \
        _Pragma("unroll")                                                      \
        for (int f = 0; f < 4; ++f) {                                          \
            f32x4 a = acc[cf][f];                                              \
            a = __builtin_amdgcn_mfma_f32_16x16x32_bf16(v0, pg[f][0], a, 0, 0, 0); \
            a = __builtin_amdgcn_mfma_f32_16x16x32_bf16(v1, pg[f][1], a, 0, 0, 0); \
            acc[cf][f] = a;                                                    \
        }                                                                      \
    }                                                                          \
} while (0)

__global__ __launch_bounds__(512, 2) void attn_kernel(
    const unsigned short* __restrict__ Qh, const unsigned short* __restrict__ Kh,
    const unsigned short* __restrict__ Vb,
    const float* __restrict__ x, const float* __restrict__ gamma,
    float* __restrict__ out)
{
    extern __shared__ char smem[];
    char* const Kb = smem;                       // 4 x 8KB K tiles, swizzled
    char* const Pb = smem + 32768;               // 4 x 16KB P tiles, swizzled
    float* const sF = (float*)(smem + 98304);    // sFac[4][64]
    float* const sL = (float*)(smem + 99328);    // [64]

    // XCD swizzle: 2 XCDs per batch
    const int bid = blockIdx.x;
    const int b   = (bid & 7) >> 1;
    const int it  = (bid >> 3) + ((bid & 1) << 5);
    const int i0  = it * 64;

    const int t   = threadIdx.x;
    const int wv8 = t >> 6;
    const bool isProd = (wv8 < 4);
    const int w   = wv8 & 3;
    const int l   = t & 63, g = l >> 4, m = l & 15;
    const int irow = w * 16 + m;

    // ---- prologue: cooperative stage of K tiles 0 and 1 ----
    {
        int sj = t >> 2, sq = t & 3;
        int wr = sj * 64 + ((sq * 16) ^ (((sj >> 1) & 3) << 4));
        const size_t gb = ((size_t)b * NPIX + sj) * CQK + sq * 8;
        *(uint4*)&Kb[wr]        = *(const uint4*)&Kh[gb];
        *(uint4*)&Kb[8192 + wr] = *(const uint4*)&Kh[gb + (size_t)128 * CQK];
    }

    // ---- producer state ----
    short8 qh = {};
    float m_run = -1e30f, l_run = 0.f;
    if (isProd) {
        const int iq = i0 + irow;
        qh = __builtin_bit_cast(short8, *(const uint4*)&Qh[((size_t)b * NPIX + iq) * CQK + g * 8]);
    }

    // ---- consumer state ----
    f32x4 acc[4][4];
    #pragma unroll
    for (int cf = 0; cf < 4; ++cf)
        #pragma unroll
        for (int f = 0; f < 4; ++f) acc[cf][f] = (f32x4){0.f, 0.f, 0.f, 0.f};
    const unsigned short* vrow[4];
    uint4 vAc[8], vAd[8];
    uint4 pkA0 = {}, pkA1 = {}, pkB0 = {}, pkB1 = {};
    size_t kpf_base = 0;
    int kwr0 = 0;
    if (!isProd) {
        #pragma unroll
        for (int cf = 0; cf < 4; ++cf)
            vrow[cf] = Vb + ((size_t)b * CH + w * 64 + cf * 16 + m) * NPIX;
        const int t2  = t & 255;
        const int sj0 = t2 >> 2, sq0 = t2 & 3;
        kpf_base = ((size_t)b * NPIX + sj0) * CQK + sq0 * 8;
        kwr0 = sj0 * 64 + ((sq0 * 16) ^ (((sj0 >> 1) & 3) << 4));
        // V pipeline prologue: tiles 0 and 1, first halves
        #pragma unroll
        for (int cf = 0; cf < 4; ++cf) {
            vAc[cf * 2]     = *(const uint4*)&vrow[cf][g * 8];
            vAc[cf * 2 + 1] = *(const uint4*)&vrow[cf][32 + g * 8];
            vAd[cf * 2]     = *(const uint4*)&vrow[cf][128 + g * 8];
            vAd[cf * 2 + 1] = *(const uint4*)&vrow[cf][160 + g * 8];
        }
        // K pipeline prologue: tiles 2 and 3 into held regs
        pkA0 = *(const uint4*)&Kh[kpf_base + (size_t)(2 * 128) * CQK];
        pkA1 = *(const uint4*)&Kh[kpf_base + (size_t)(2 * 128) * CQK + 2048];
        pkB0 = *(const uint4*)&Kh[kpf_base + (size_t)(3 * 128) * CQK];
        pkB1 = *(const uint4*)&Kh[kpf_base + (size_t)(3 * 128) * CQK + 2048];
    }

    __syncthreads();

    for (int T = 0; T < NT / 2; ++T) {
        if (isProd) {
            PROD_STEP(2 * T);
            PROD_STEP(2 * T + 1);
        } else {
            // ds_write K tiles 2T+2, 2T+3 (regs from prologue / superstep T-1)
            if (T < NT / 2 - 1) {
                char* ka = Kb + ((2 * T + 2) & 3) * 8192;
                char* kc = Kb + ((2 * T + 3) & 3) * 8192;
                *(uint4*)&ka[kwr0] = pkA0;
                *(uint4*)&ka[kwr0 + 4096] = pkA1;
                *(uint4*)&kc[kwr0] = pkB0;
                *(uint4*)&kc[kwr0 + 4096] = pkB1;
            }
            // issue K loads for tiles 2T+4, 2T+5 (stay in flight over barrier)
            uint4 nA0, nA1, nB0, nB1;
            const bool doK = (T < NT / 2 - 2);
            if (doK) {
                nA0 = *(const uint4*)&Kh[kpf_base + (size_t)((2 * T + 4) * 128) * CQK];
                nA1 = *(const uint4*)&Kh[kpf_base + (size_t)((2 * T + 4) * 128) * CQK + 2048];
                nB0 = *(const uint4*)&Kh[kpf_base + (size_t)((2 * T + 5) * 128) * CQK];
                nB1 = *(const uint4*)&Kh[kpf_base + (size_t)((2 * T + 5) * 128) * CQK + 2048];
            }

            if (T >= 1) {
                CONS_PV(2 * T - 2, vAc, true);
                CONS_PV(2 * T - 1, vAd, true);
            }

            if (doK) { pkA0 = nA0; pkA1 = nA1; pkB0 = nB0; pkB1 = nB1; }
        }

        barrier_lgkm_only();
    }

    // ---- tail: publish denominators, final 2 PVs, epilogue ----
    if (isProd) {
        if (g == 0) sL[irow] = l_run;
    }
    __syncthreads();
    if (!isProd) {
        CONS_PV(NT - 2, vAc, false);
        CONS_PV(NT - 1, vAd, false);
        const float gm = gamma[0];
        #pragma unroll
        for (int f = 0; f < 4; ++f) {
            float linv = 1.0f / sL[f * 16 + m];
            #pragma unroll
            for (int cf = 0; cf < 4; ++cf) {
                #pragma unroll
                for (int r = 0; r < 4; ++r) {
                    int c = w * 64 + cf * 16 + g * 4 + r;
                    size_t o = ((size_t)b * CH + c) * NPIX + i0 + f * 16 + m;
                    out[o] = gm * acc[cf][f][r] * linv + x[o];
                }
            }
        }
    }
}

extern "C" void kernel_launch(void* const* d_in, const int* in_sizes, int n_in,
                              void* d_out, int out_size, void* d_ws, size_t ws_size,
                              hipStream_t stream) {
    const float* x     = (const float*)d_in[0];
    const float* wq    = (const float*)d_in[1];
    const float* bq    = (const float*)d_in[2];
    const float* wk    = (const float*)d_in[3];
    const float* bk    = (const float*)d_in[4];
    const float* wv    = (const float*)d_in[5];
    const float* bv    = (const float*)d_in[6];
    const float* gamma = (const float*)d_in[7];
    float* out = (float*)d_out;

    // ws layout (bf16): Qh|Kh (1MB each) | Vb (8MB) | Wh|Wl (160KB each)
    unsigned short* base = (unsigned short*)d_ws;
    const size_t qk_sz = (size_t)BATCH * NPIX * CQK;   // 524288
    unsigned short* Qh = base;
    unsigned short* Kh = Qh + qk_sz;
    unsigned short* Vb = Kh + qk_sz;
    unsigned short* Wh = Vb + (size_t)BATCH * CH * NPIX;
    unsigned short* Wl = Wh + 320 * 256;

    wcvt_kernel<<<320, 256, 0, stream>>>(wq, wk, wv, Wh, Wl);
    qkv_kernel<<<dim3(64, 4), 256, 65536, stream>>>(x, bq, bk, bv, Wh, Wl,
                                                    Qh, Kh, Vb);
    attn_kernel<<<256, 512, 99584, stream>>>(Qh, Kh, Vb, x, gamma, out);
}

// Round 17
// 89.377 us; speedup vs baseline: 1.6515x; 1.6515x over previous
//
#include <hip/hip_runtime.h>
#include <math.h>

#define BATCH 4
#define CH    256
#define CQK   32
#define NPIX  4096   // 64*64
#define NT    32     // KV steps of 128 keys each
#define LOG2E 1.4426950408889634f

typedef __attribute__((ext_vector_type(8))) short short8;   // 8 bf16 (4 VGPRs)
typedef __attribute__((ext_vector_type(4))) float f32x4;

static __device__ __forceinline__ unsigned short f2bf(float f) {
    unsigned u = __builtin_bit_cast(unsigned, f);
    u = (u + 0x7fffu + ((u >> 16) & 1u)) >> 16;   // RNE
    return (unsigned short)u;
}
static __device__ __forceinline__ float bf2f(unsigned short s) {
    unsigned u = ((unsigned)s) << 16;
    return __builtin_bit_cast(float, u);
}
static __device__ __forceinline__ float exp2_fast(float x) {
    float r; asm("v_exp_f32 %0, %1" : "=v"(r) : "v"(x)); return r;
}
static __device__ __forceinline__ unsigned cvt_pk_bf16(float lo, float hi) {
    unsigned r; asm("v_cvt_pk_bf16_f32 %0, %1, %2" : "=v"(r) : "v"(lo), "v"(hi)); return r;
}

// ---------------------------------------------------------------------------
// Kernel 0: W -> bf16 (single plane). Q rows pre-scaled by log2(e).
//   R13 proved absmax is dominated by P/V bf16 quantization (dropping Ql
//   moved it by 0); single-bf16 W/x adds ~0.3% relative on scores -> ~0.003
//   on out, far under the 0.1 threshold.
// ---------------------------------------------------------------------------
__global__ __launch_bounds__(256) void wcvt_kernel(
    const float* __restrict__ wq, const float* __restrict__ wk,
    const float* __restrict__ wv,
    unsigned short* __restrict__ Wh)
{
    int idx = blockIdx.x * 256 + threadIdx.x;   // 0..81919
    int r = idx >> 8, c = idx & 255;
    float f;
    if (r < 32)       f = wq[r * 256 + c] * LOG2E;
    else if (r < 64)  f = wk[(r - 32) * 256 + c];
    else              f = wv[(r - 64) * 256 + c];
    Wh[idx] = f2bf(f);
}

// ---------------------------------------------------------------------------
// Kernel 1: q/k/v projections, single-bf16 MFMA GEMM, n-tile = 64.
//   Grid (64, 4), 256 threads, static LDS 32KB (Xh, swizzled [n][c]).
//   Outputs: Qh, Kh [b][n][32]; Vb [b][c][n].
// ---------------------------------------------------------------------------
__global__ __launch_bounds__(256) void qkv_kernel(
    const float* __restrict__ x,
    const float* __restrict__ bq, const float* __restrict__ bk,
    const float* __restrict__ bv,
    const unsigned short* __restrict__ Wh,
    unsigned short* __restrict__ Qh, unsigned short* __restrict__ Kh,
    unsigned short* __restrict__ Vb)
{
    __shared__ __align__(16) char Xh[64 * 512];   // 64 rows x 512B, swizzled

    const int b  = blockIdx.y;
    const int n0 = blockIdx.x * 64;
    const int t  = threadIdx.x;

    // ---- stage x tile: 128 c-pairs x 16 float4-groups = 2048 items ----
    #pragma unroll
    for (int rep = 0; rep < 8; ++rep) {
        int idx = rep * 256 + t;
        int cp = idx >> 4, n4 = idx & 15;        // cp = c/2
        int c = cp * 2;
        float4 a4 = *(const float4*)&x[((size_t)b * CH + c) * NPIX + n0 + n4 * 4];
        float4 b4 = *(const float4*)&x[((size_t)b * CH + c + 1) * NPIX + n0 + n4 * 4];
        #pragma unroll
        for (int u = 0; u < 4; ++u) {
            int n = n4 * 4 + u;
            int off = n * 512 + (((c >> 3) * 16) ^ ((n & 7) << 4)) + (c & 7) * 2;
            *(unsigned*)(Xh + off) =
                (unsigned)f2bf((&a4.x)[u]) | ((unsigned)f2bf((&b4.x)[u]) << 16);
        }
    }
    __syncthreads();

    const int w = t >> 6, l = t & 63, g = l >> 4, m = l & 15;

    for (int dt = 0; dt < 5; ++dt) {
        const int d0 = w * 80 + dt * 16;

        short8 wh[8];
        #pragma unroll
        for (int ks = 0; ks < 8; ++ks) {
            size_t off = (size_t)(d0 + m) * 256 + ks * 32 + g * 8;
            wh[ks] = __builtin_bit_cast(short8, *(const uint4*)&Wh[off]);
        }

        f32x4 acc[4];
        #pragma unroll
        for (int nt = 0; nt < 4; ++nt) acc[nt] = (f32x4){0.f, 0.f, 0.f, 0.f};
        #pragma unroll
        for (int nt = 0; nt < 4; ++nt) {
            const int n = nt * 16 + m;
            #pragma unroll
            for (int ks = 0; ks < 8; ++ks) {
                int off = n * 512 + (((ks * 4 + g) * 16) ^ ((n & 7) << 4));
                short8 xh = __builtin_bit_cast(short8, *(const uint4*)(Xh + off));
                acc[nt] = __builtin_amdgcn_mfma_f32_16x16x32_bf16(wh[ks], xh, acc[nt], 0, 0, 0);
            }
        }

        int kind;                      // 0=Q, 1=K, 2=V
        float4 bias;
        if (d0 < 32)      { kind = 0; bias = *(const float4*)&bq[d0 + g * 4];
                            bias.x *= LOG2E; bias.y *= LOG2E; bias.z *= LOG2E; bias.w *= LOG2E; }
        else if (d0 < 64) { kind = 1; bias = *(const float4*)&bk[d0 - 32 + g * 4]; }
        else              { kind = 2; bias = *(const float4*)&bv[d0 - 64 + g * 4]; }

        #pragma unroll
        for (int nt = 0; nt < 4; ++nt) {
            const int n = n0 + nt * 16 + m;
            if (kind == 2) {
                const int c0 = d0 - 64;
                #pragma unroll
                for (int r = 0; r < 4; ++r) {
                    float val = acc[nt][r] + (&bias.x)[r];
                    Vb[((size_t)b * CH + c0 + g * 4 + r) * NPIX + n] = f2bf(val);
                }
            } else {
                unsigned short hs[4];
                #pragma unroll
                for (int r = 0; r < 4; ++r)
                    hs[r] = f2bf(acc[nt][r] + (&bias.x)[r]);
                const int dcol = (d0 & 31) + g * 4;
                const size_t base = ((size_t)b * NPIX + n) * CQK + dcol;
                uint2 uh;
                uh.x = (unsigned)hs[0] | ((unsigned)hs[1] << 16);
                uh.y = (unsigned)hs[2] | ((unsigned)hs[3] << 16);
                if (kind == 0) *(uint2*)&Qh[base] = uh;
                else           *(uint2*)&Kh[base] = uh;
            }
        }
    }
}

// ---------------------------------------------------------------------------
// Kernel 2: flash attention, producer/consumer waves, KVBLK = 128.
//   EXACT R14 (best measured: 74.0 us): single-bf16 QK^T, gated defer-max
//   base-2 softmax, V software pipeline + sFac hoist, K tile swizzled
//   (((row>>1)&3)<<4), one __syncthreads per step.
// ---------------------------------------------------------------------------

#define CONS_STEP(JT, PF) do {                                                 \
    const int _jb   = ((JT) - 1) * 128;                                        \
    const int _pidx = ((JT) & 1) ^ 1;                                          \
    const char* pb = (const char*)Pbuf[_pidx];                                 \
    float ff[4];                                                               \
    _Pragma("unroll")                                                          \
    for (int f = 0; f < 4; ++f) ff[f] = sFac[_pidx][f * 16 + m];               \
    uint4 vB[8];                                                               \
    _Pragma("unroll")                                                          \
    for (int cf = 0; cf < 4; ++cf) {                                           \
        vB[cf * 2]     = *(const uint4*)&vrow[cf][_jb + 64 + g * 8];           \
        vB[cf * 2 + 1] = *(const uint4*)&vrow[cf][_jb + 96 + g * 8];           \
    }                                                                          \
    short8 pf[4][2];                                                           \
    _Pragma("unroll")                                                          \
    for (int f = 0; f < 4; ++f)                                                \
        _Pragma("unroll")                                                      \
        for (int k2 = 0; k2 < 2; ++k2)                                         \
            pf[f][k2] = __builtin_bit_cast(short8, *(const uint4*)(pb +        \
                (f * 16 + m) * 256 + ((k2 * 64 + g * 16) ^ (m << 4))));        \
    if (!__all(ff[0] == 1.f && ff[1] == 1.f && ff[2] == 1.f && ff[3] == 1.f)) { \
        _Pragma("unroll")                                                      \
        for (int cf = 0; cf < 4; ++cf)                                         \
            _Pragma("unroll")                                                  \
            for (int f = 0; f < 4; ++f) acc[cf][f] *= ff[f];                   \
    }                                                                          \
    _Pragma("unroll")                                                          \
    for (int cf = 0; cf < 4; ++cf) {                                           \
        short8 v0 = __builtin_bit_cast(short8, vAc[cf * 2]);                   \
        short8 v1 = __builtin_bit_cast(short8, vAc[cf * 2 + 1]);               \
        _Pragma("unroll")                                                      \
        for (int f = 0; f < 4; ++f) {                                          \
            f32x4 a = acc[cf][f];                                              \
            a = __builtin_amdgcn_mfma_f32_16x16x32_bf16(v0, pf[f][0], a, 0, 0, 0); \
            a = __builtin_amdgcn_mfma_f32_16x16x32_bf16(v1, pf[f][1], a, 0, 0, 0); \
            acc[cf][f] = a;                                                    \
        }                                                                      \
    }                                                                          \
    if (PF) {                                                                  \
        _Pragma("unroll")                                                      \
        for (int cf = 0; cf < 4; ++cf) {                                       \
            vAc[cf * 2]     = *(const uint4*)&vrow[cf][_jb + 128 + g * 8];     \
            vAc[cf * 2 + 1] = *(const uint4*)&vrow[cf][_jb + 160 + g * 8];     \
        }                                                                      \
    }                                                                          \
    short8 pg[4][2];                                                           \
    _Pragma("unroll")                                                          \
    for (int f = 0; f < 4; ++f)                                                \
        _Pragma("unroll")                                                      \
        for (int k2 = 0; k2 < 2; ++k2)                                         \
            pg[f][k2] = __builtin_bit_cast(short8, *(const uint4*)(pb +        \
                (f * 16 + m) * 256 + (((k2 + 2) * 64 + g * 16) ^ (m << 4))));  \
    _Pragma("unroll")                                                          \
    for (int cf = 0; cf < 4; ++cf) {                                           \
        short8 v0 = __builtin_bit_cast(short8, vB[cf * 2]);                    \
        short8 v1 = __builtin_bit_cast(short8, vB[cf * 2 + 1]);                \
        _Pragma("unroll")                                                      \
        for (int f = 0; f < 4; ++f) {                                          \
            f32x4 a = acc[cf][f];                                              \
            a = __builtin_amdgcn_mfma_f32_16x16x32_bf16(v0, pg[f][0], a, 0, 0, 0); \
            a = __builtin_amdgcn_mfma_f32_16x16x32_bf16(v1, pg[f][1], a, 0, 0, 0); \
            acc[cf][f] = a;                                                    \
        }                                                                      \
    }                                                                          \
} while (0)

__global__ __launch_bounds__(512, 2) void attn_kernel(
    const unsigned short* __restrict__ Qh, const unsigned short* __restrict__ Kh,
    const unsigned short* __restrict__ Vb,
    const float* __restrict__ x, const float* __restrict__ gamma,
    float* __restrict__ out)
{
    __shared__ __align__(16) char Ksw[2][8192];    // K tile: 128 rows x 64B, swizzled
    __shared__ __align__(16) uint4 Pbuf[2][1024];  // P: 64 rows x 256B, swizzled
    __shared__ float sFac[2][64];
    __shared__ float sL[64];

    // XCD swizzle: 2 XCDs per batch
    const int bid = blockIdx.x;
    const int b   = (bid & 7) >> 1;
    const int it  = (bid >> 3) + ((bid & 1) << 5);
    const int i0  = it * 64;

    const int t   = threadIdx.x;
    const int wv8 = t >> 6;
    const bool isProd = (wv8 < 4);
    const int w   = wv8 & 3;
    const int l   = t & 63, g = l >> 4, m = l & 15;
    const int irow = w * 16 + m;

    // ---- prologue: stage K tile 0 (8KB, 512 x uint4, swizzled rows) ----
    {
        int sj = t >> 2, sq = t & 3;
        int wr = sj * 64 + ((sq * 16) ^ (((sj >> 1) & 3) << 4));
        *(uint4*)&Ksw[0][wr] =
            *(const uint4*)&Kh[((size_t)b * NPIX + sj) * CQK + sq * 8];
    }

    // ---- producer state ----
    short8 qh = {};
    float m_run = -1e30f, l_run = 0.f;
    if (isProd) {
        const int iq = i0 + irow;
        qh = __builtin_bit_cast(short8, *(const uint4*)&Qh[((size_t)b * NPIX + iq) * CQK + g * 8]);
    }

    // ---- consumer state ----
    f32x4 acc[4][4];
    #pragma unroll
    for (int cf = 0; cf < 4; ++cf)
        #pragma unroll
        for (int f = 0; f < 4; ++f) acc[cf][f] = (f32x4){0.f, 0.f, 0.f, 0.f};
    const unsigned short* vrow[4];
    uint4 vAc[8];
    size_t kpf_base = 0;
    int kwr0 = 0;
    if (!isProd) {
        #pragma unroll
        for (int cf = 0; cf < 4; ++cf)
            vrow[cf] = Vb + ((size_t)b * CH + w * 64 + cf * 16 + m) * NPIX;
        const int t2  = t & 255;
        const int sj0 = t2 >> 2, sq0 = t2 & 3;
        kpf_base = ((size_t)b * NPIX + sj0) * CQK + sq0 * 8;
        kwr0 = sj0 * 64 + ((sq0 * 16) ^ (((sj0 >> 1) & 3) << 4));
        // V pipeline prologue: tile 0, first half
        #pragma unroll
        for (int cf = 0; cf < 4; ++cf) {
            vAc[cf * 2]     = *(const uint4*)&vrow[cf][g * 8];
            vAc[cf * 2 + 1] = *(const uint4*)&vrow[cf][32 + g * 8];
        }
    }

    __syncthreads();

    for (int jt = 0; jt < NT; ++jt) {
        const int idx = jt & 1;

        if (isProd) {
            // ---- QK^T: 8 j-tiles x 1 MFMA (swizzled K read, 2-way max) ----
            f32x4 sv[8];
            #pragma unroll
            for (int jf = 0; jf < 8; ++jf) {
                short8 kh8 = __builtin_bit_cast(short8,
                    *(const uint4*)&Ksw[idx][jf * 1024 + m * 64 +
                        ((g * 16) ^ (((m >> 1) & 3) << 4))]);
                f32x4 s = (f32x4){0.f, 0.f, 0.f, 0.f};
                s = __builtin_amdgcn_mfma_f32_16x16x32_bf16(kh8, qh, s, 0, 0, 0);
                sv[jf] = s;
            }

            float s32[32];
            #pragma unroll
            for (int jf = 0; jf < 8; ++jf)
                #pragma unroll
                for (int r = 0; r < 4; ++r) s32[jf * 4 + r] = sv[jf][r];

            // ---- in-lane tree max ----
            float mx[16];
            #pragma unroll
            for (int k = 0; k < 16; ++k) mx[k] = fmaxf(s32[k], s32[k + 16]);
            #pragma unroll
            for (int k = 0; k < 8; ++k) mx[k] = fmaxf(mx[k], mx[k + 8]);
            #pragma unroll
            for (int k = 0; k < 4; ++k) mx[k] = fmaxf(mx[k], mx[k + 4]);
            float tmax = fmaxf(fmaxf(mx[0], mx[2]), fmaxf(mx[1], mx[3]));

            // ---- gated defer-max: cross-lane max only when vote fails ----
            float fac = 1.0f;
            if (!__all(tmax <= m_run + 11.5f)) {
                float tc = fmaxf(tmax, __shfl_xor(tmax, 16));
                tc = fmaxf(tc, __shfl_xor(tc, 32));
                float mt = fmaxf(m_run, tc);
                fac = exp2_fast(m_run - mt);
                m_run = mt;
            }

            float p[32];
            #pragma unroll
            for (int k = 0; k < 32; ++k) p[k] = exp2_fast(s32[k] - m_run);
            float sm[16];
            #pragma unroll
            for (int k = 0; k < 16; ++k) sm[k] = p[k] + p[k + 16];
            #pragma unroll
            for (int k = 0; k < 8; ++k) sm[k] = sm[k] + sm[k + 8];
            #pragma unroll
            for (int k = 0; k < 4; ++k) sm[k] = sm[k] + sm[k + 4];
            float tsum = (sm[0] + sm[2]) + (sm[1] + sm[3]);
            tsum += __shfl_xor(tsum, 16);
            tsum += __shfl_xor(tsum, 32);
            l_run = l_run * fac + tsum;
            if (g == 0) sFac[idx][irow] = fac;

            // ---- pack P -> bf16, swizzled ----
            char* pb = (char*)Pbuf[idx];
            #pragma unroll
            for (int jf = 0; jf < 8; ++jf) {
                uint2 u;
                u.x = cvt_pk_bf16(p[jf * 4 + 0], p[jf * 4 + 1]);
                u.y = cvt_pk_bf16(p[jf * 4 + 2], p[jf * 4 + 3]);
                *(uint2*)(pb + irow * 256 + ((jf * 32 + g * 8) ^ (m << 4))) = u;
            }
        } else {
            const bool doK = (jt < NT - 1);
            uint4 pk0, pk1;
            if (doK) {
                const size_t rb = kpf_base + (size_t)((jt + 1) * 128) * CQK;
                pk0 = *(const uint4*)&Kh[rb];
                pk1 = *(const uint4*)&Kh[rb + 2048];
            }

            if (jt >= 1) CONS_STEP(jt, true);

            if (doK) {
                *(uint4*)&Ksw[idx ^ 1][kwr0] = pk0;
                *(uint4*)&Ksw[idx ^ 1][kwr0 + 4096] = pk1;
            }
        }

        __syncthreads();
    }

    // ---- tail: publish denominators, final PV, epilogue ----
    if (isProd) {
        if (g == 0) sL[irow] = l_run;
    }
    __syncthreads();
    if (!isProd) {
        CONS_STEP(NT, false);
        const float gm = gamma[0];
        #pragma unroll
        for (int f = 0; f < 4; ++f) {
            float linv = 1.0f / sL[f * 16 + m];
            #pragma unroll
            for (int cf = 0; cf < 4; ++cf) {
                #pragma unroll
                for (int r = 0; r < 4; ++r) {
                    int c = w * 64 + cf * 16 + g * 4 + r;
                    size_t o = ((size_t)b * CH + c) * NPIX + i0 + f * 16 + m;
                    out[o] = gm * acc[cf][f][r] * linv + x[o];
                }
            }
        }
    }
}

extern "C" void kernel_launch(void* const* d_in, const int* in_sizes, int n_in,
                              void* d_out, int out_size, void* d_ws, size_t ws_size,
                              hipStream_t stream) {
    const float* x     = (const float*)d_in[0];
    const float* wq    = (const float*)d_in[1];
    const float* bq    = (const float*)d_in[2];
    const float* wk    = (const float*)d_in[3];
    const float* bk    = (const float*)d_in[4];
    const float* wv    = (const float*)d_in[5];
    const float* bv    = (const float*)d_in[6];
    const float* gamma = (const float*)d_in[7];
    float* out = (float*)d_out;

    // ws layout (bf16): Qh|Kh (1MB each) | Vb (8MB) | Wh (160KB)
    unsigned short* base = (unsigned short*)d_ws;
    const size_t qk_sz = (size_t)BATCH * NPIX * CQK;   // 524288
    unsigned short* Qh = base;
    unsigned short* Kh = Qh + qk_sz;
    unsigned short* Vb = Kh + qk_sz;
    unsigned short* Wh = Vb + (size_t)BATCH * CH * NPIX;

    wcvt_kernel<<<320, 256, 0, stream>>>(wq, wk, wv, Wh);
    qkv_kernel<<<dim3(64, 4), 256, 0, stream>>>(x, bq, bk, bv, Wh, Qh, Kh, Vb);
    attn_kernel<<<256, 512, 0, stream>>>(Qh, Kh, Vb, x, gamma, out);
}